// Round 3
// baseline (507.669 us; speedup 1.0000x reference)
//
#include <hip/hip_runtime.h>
#include <stdint.h>

#define DIM    680
#define DPAD   768      // 3 x 256 tiles
#define NCH    864      // 55296 / 64 g-chunks
#define NB_Q   24
#define SPLITS 72
#define STAGES 12       // NCH / SPLITS
#define NTILE  6        // upper-triangle 256x256 tiles of 3x3

typedef __bf16 bf16x8 __attribute__((ext_vector_type(8)));
typedef float  f32x16 __attribute__((ext_vector_type(16)));

__constant__ int c_tj[NTILE] = {0, 0, 0, 1, 1, 2};
__constant__ int c_ti[NTILE] = {0, 1, 2, 1, 2, 2};

static __device__ __forceinline__ unsigned f2bf(float x) {
    union { float f; unsigned u; } c; c.f = x;
    unsigned u = c.u;
    return (u + 0x7FFFu + ((u >> 16) & 1u)) >> 16;  // RNE
}

static __device__ __forceinline__ float bf2f(unsigned short h) {
    union { unsigned u; float f; } c; c.u = ((unsigned)h) << 16;
    return c.f;
}

// ---------------------------------------------------------------------------
// k1: D (55296 x 680 fp32) -> Awt bf16, scaled by sqrt(qw[b]), chunk-transposed:
//     16B slot (chunk cg, col i, kc) at uint4 index ((cg*768 + i)*8 + (kc ^ (i&7)))
//     holding g = cg*64 + kc*8 + 0..7 of column i.  Cols 680..767 zero-padded.
//     4 chunks per block, register-prefetch pipelined over the pack phase.
// ---------------------------------------------------------------------------
__global__ __launch_bounds__(256) void k1_transpose(
        const float* __restrict__ D, const float* __restrict__ qw,
        uint4* __restrict__ awt) {
    __shared__ float sq[NB_Q];
    __shared__ float tile[64][65];
    const int t   = threadIdx.x;
    const int cg0 = blockIdx.x * 4;
    const int i0  = blockIdx.y * 64;
    if (t < NB_Q) sq[t] = sqrtf(qw[t]);

    const int rb   = t >> 4;
    const int c4   = (t & 15) * 4;
    const int colg = i0 + c4;
    const int pc   = (t + 256) >> 3;   // pack-phase col for s=1
    const int c0   = t >> 3;           // pack-phase col for s=0
    const int kc   = t & 7;

    float4 v[4];
#pragma unroll
    for (int j = 0; j < 4; ++j) {
        const int g = cg0 * 64 + rb + j * 16;
        if (colg + 3 < DIM) {
            v[j] = *reinterpret_cast<const float4*>(D + (size_t)g * DIM + colg);
        } else {
            v[j].x = (colg + 0 < DIM) ? D[(size_t)g * DIM + colg + 0] : 0.f;
            v[j].y = (colg + 1 < DIM) ? D[(size_t)g * DIM + colg + 1] : 0.f;
            v[j].z = (colg + 2 < DIM) ? D[(size_t)g * DIM + colg + 2] : 0.f;
            v[j].w = (colg + 3 < DIM) ? D[(size_t)g * DIM + colg + 3] : 0.f;
        }
    }
    __syncthreads();   // sq ready; harmless for tile

#pragma unroll
    for (int cc = 0; cc < 4; ++cc) {
        const int cg = cg0 + cc;
        const int g0 = cg * 64;
#pragma unroll
        for (int j = 0; j < 4; ++j) {
            const int r = rb + j * 16;
            const float w = sq[((g0 + r) / 48) % 24];
            tile[r][c4 + 0] = v[j].x * w;
            tile[r][c4 + 1] = v[j].y * w;
            tile[r][c4 + 2] = v[j].z * w;
            tile[r][c4 + 3] = v[j].w * w;
        }
        __syncthreads();
        if (cc < 3) {   // prefetch next chunk while this one is packed
#pragma unroll
            for (int j = 0; j < 4; ++j) {
                const int g = (cg + 1) * 64 + rb + j * 16;
                if (colg + 3 < DIM) {
                    v[j] = *reinterpret_cast<const float4*>(D + (size_t)g * DIM + colg);
                } else {
                    v[j].x = (colg + 0 < DIM) ? D[(size_t)g * DIM + colg + 0] : 0.f;
                    v[j].y = (colg + 1 < DIM) ? D[(size_t)g * DIM + colg + 1] : 0.f;
                    v[j].z = (colg + 2 < DIM) ? D[(size_t)g * DIM + colg + 2] : 0.f;
                    v[j].w = (colg + 3 < DIM) ? D[(size_t)g * DIM + colg + 3] : 0.f;
                }
            }
        }
#pragma unroll
        for (int s = 0; s < 2; ++s) {
            const int c = s ? pc : c0;
            uint4 o;
            o.x = f2bf(tile[kc * 8 + 0][c]) | (f2bf(tile[kc * 8 + 1][c]) << 16);
            o.y = f2bf(tile[kc * 8 + 2][c]) | (f2bf(tile[kc * 8 + 3][c]) << 16);
            o.z = f2bf(tile[kc * 8 + 4][c]) | (f2bf(tile[kc * 8 + 5][c]) << 16);
            o.w = f2bf(tile[kc * 8 + 6][c]) | (f2bf(tile[kc * 8 + 7][c]) << 16);
            const size_t slot = ((size_t)cg * DPAD + (size_t)(i0 + c)) * 8
                              + (size_t)(kc ^ (c & 7));
            awt[slot] = o;
        }
        __syncthreads();
    }
}

// ---------------------------------------------------------------------------
// k2: partial[split][tile] = sum over this split's 12 chunks of
//     A_band(tj)^T * A_band(ti), upper-triangle tiles only (M symmetric).
//     grid (72 splits, 6 tiles), 512 threads = 8 waves (4 m x 2 n),
//     wave tile 64x128, mfma_f32_32x32x16_bf16.
//     Epilogue: row-quad-packed uint2 stores — u64 word w = quad*256 + col
//     holds rows 4*quad..+3 of col; half-wave = 256 B fully-written lines.
// ---------------------------------------------------------------------------
__global__ __launch_bounds__(512) void k2_gram(const uint4* __restrict__ awt,
                                               uint2* __restrict__ parts) {
    __shared__ uint4 smA[2048];   // 256 cols x 8 slots (swizzled), 32 KB
    __shared__ uint4 smB[2048];
    const int t     = threadIdx.x;
    const int split = blockIdx.x;
    const int t6    = blockIdx.y;
    const int tj    = c_tj[t6];   // row band of M
    const int ti    = c_ti[t6];   // col band of M
    const int wave  = t >> 6;
    const int lane  = t & 63;
    const int wm    = wave & 3;   // m: 64-row band
    const int wn    = wave >> 2;  // n: 128-col band
    const int cl    = lane & 31;
    const int half  = lane >> 5;

    f32x16 acc[2][4];
    const f32x16 zero = {};
#pragma unroll
    for (int a = 0; a < 2; ++a)
#pragma unroll
        for (int b = 0; b < 4; ++b) acc[a][b] = zero;

    uint4 ra[4], rb4[4];
    {
        const size_t bA = ((size_t)(split * STAGES) * DPAD + tj * 256) * 8;
        const size_t bB = ((size_t)(split * STAGES) * DPAD + ti * 256) * 8;
#pragma unroll
        for (int j = 0; j < 4; ++j) {
            ra[j]  = awt[bA + j * 512 + t];
            rb4[j] = awt[bB + j * 512 + t];
        }
    }

    for (int st = 0; st < STAGES; ++st) {
        __syncthreads();
#pragma unroll
        for (int j = 0; j < 4; ++j) {
            smA[j * 512 + t] = ra[j];
            smB[j * 512 + t] = rb4[j];
        }
        __syncthreads();
        if (st + 1 < STAGES) {  // prefetch next stage into registers
            const int cg = split * STAGES + st + 1;
            const size_t bA = ((size_t)cg * DPAD + tj * 256) * 8;
            const size_t bB = ((size_t)cg * DPAD + ti * 256) * 8;
#pragma unroll
            for (int j = 0; j < 4; ++j) {
                ra[j]  = awt[bA + j * 512 + t];
                rb4[j] = awt[bB + j * 512 + t];
            }
        }
        const bf16x8* pA = reinterpret_cast<const bf16x8*>(smA);
        const bf16x8* pB = reinterpret_cast<const bf16x8*>(smB);
#pragma unroll
        for (int t4 = 0; t4 < 4; ++t4) {          // K = 64 per stage, 16/mfma
            const int kc = 2 * t4 + half;
            bf16x8 af[2], bfr[4];
#pragma unroll
            for (int ms = 0; ms < 2; ++ms) {
                const int col = wm * 64 + ms * 32 + cl;
                af[ms] = pA[col * 8 + (kc ^ (col & 7))];
            }
#pragma unroll
            for (int ns = 0; ns < 4; ++ns) {
                const int col = wn * 128 + ns * 32 + cl;
                bfr[ns] = pB[col * 8 + (kc ^ (col & 7))];
            }
#pragma unroll
            for (int ms = 0; ms < 2; ++ms)
#pragma unroll
                for (int ns = 0; ns < 4; ++ns)
                    acc[ms][ns] = __builtin_amdgcn_mfma_f32_32x32x16_bf16(
                        af[ms], bfr[ns], acc[ms][ns], 0, 0, 0);
        }
    }

    // row-quad packed bf16 stores: full-line coalesced, no atomics
    uint2* pt = parts + (size_t)(split * NTILE + t6) * 16384;
#pragma unroll
    for (int ms = 0; ms < 2; ++ms) {
        const int rowb = wm * 64 + ms * 32 + 4 * half;   // multiple of 4
#pragma unroll
        for (int ns = 0; ns < 4; ++ns) {
            const int colt = wn * 128 + ns * 32 + cl;
#pragma unroll
            for (int q = 0; q < 4; ++q) {                // rows rowb+8q .. +3
                uint2 w;
                w.x = f2bf(acc[ms][ns][q * 4 + 0]) | (f2bf(acc[ms][ns][q * 4 + 1]) << 16);
                w.y = f2bf(acc[ms][ns][q * 4 + 2]) | (f2bf(acc[ms][ns][q * 4 + 3]) << 16);
                pt[(size_t)(((rowb >> 2) + 2 * q) * 256 + colt)] = w;
            }
        }
    }
}

// ---------------------------------------------------------------------------
// k2r: M[768x768 fp32] = sum over 72 split-partials per tile, + mirror.
//     Tile layout: u64 word w = quad*256 + col -> rows 4*quad..+3 of col.
//     grid (32, 6), 256 threads, uint4 (2 words = 2 cols x 4 rows) per thread.
// ---------------------------------------------------------------------------
__global__ __launch_bounds__(256) void k2_reduce(
        const uint2* __restrict__ parts, float* __restrict__ M) {
    const int t6 = blockIdx.y;
    const int tj = c_tj[t6];
    const int ti = c_ti[t6];
    const int idx4 = blockIdx.x * 256 + threadIdx.x;   // uint4 index, 8192/tile
    const int w0 = idx4 * 2;
    const int quad = w0 >> 8;
    const int c = w0 & 255;                            // even
    float s[8] = {0.f, 0.f, 0.f, 0.f, 0.f, 0.f, 0.f, 0.f};
    const uint4* base = reinterpret_cast<const uint4*>(parts) + idx4;
#pragma unroll 8
    for (int sp = 0; sp < SPLITS; ++sp) {
        const uint4 u = base[(size_t)(sp * NTILE + t6) * 8192];
        s[0] += bf2f((unsigned short)(u.x & 0xFFFF));
        s[1] += bf2f((unsigned short)(u.x >> 16));
        s[2] += bf2f((unsigned short)(u.y & 0xFFFF));
        s[3] += bf2f((unsigned short)(u.y >> 16));
        s[4] += bf2f((unsigned short)(u.z & 0xFFFF));
        s[5] += bf2f((unsigned short)(u.z >> 16));
        s[6] += bf2f((unsigned short)(u.w & 0xFFFF));
        s[7] += bf2f((unsigned short)(u.w >> 16));
    }
    const int R = tj * 256 + 4 * quad;
    const int C = ti * 256 + c;
#pragma unroll
    for (int i = 0; i < 4; ++i) {
        float2 d = {s[i], s[4 + i]};
        *reinterpret_cast<float2*>(M + (size_t)(R + i) * DPAD + C) = d;
    }
    if (ti != tj) {
        float4 m0 = {s[0], s[1], s[2], s[3]};
        float4 m1 = {s[4], s[5], s[6], s[7]};
        *reinterpret_cast<float4*>(M + (size_t)(C + 0) * DPAD + R) = m0;
        *reinterpret_cast<float4*>(M + (size_t)(C + 1) * DPAD + R) = m1;
    }
}

// ---------------------------------------------------------------------------
// k3: out(1024x680) = F(1024x680) @ M(768-stride).
//     fp32 tiled GEMM, 64x64 tile / block, 256 threads, 4x4 per thread.
// ---------------------------------------------------------------------------
__global__ __launch_bounds__(256) void k3_out(const float* __restrict__ F,
                                              const float* __restrict__ M,
                                              float* __restrict__ out) {
    __shared__ float Ft[32][68];   // [k][n]
    __shared__ float Ms[32][68];   // [k][i]
    const int t  = threadIdx.x;
    const int tx = t & 15;
    const int ty = t >> 4;
    const int n0 = blockIdx.x * 64;
    const int i0 = blockIdx.y * 64;
    float acc[4][4] = {};

    for (int k0 = 0; k0 < DIM; k0 += 32) {
        __syncthreads();
        {
            const int kk = t & 31;
            const int nb = t >> 5;
#pragma unroll
            for (int rr = 0; rr < 8; ++rr) {
                const int n = nb * 8 + rr;
                const int k = k0 + kk;
                Ft[kk][n] = (k < DIM) ? F[(size_t)(n0 + n) * DIM + k] : 0.f;
            }
        }
        {
            const int i  = t & 63;
            const int kb = t >> 6;
#pragma unroll
            for (int rr = 0; rr < 8; ++rr) {
                const int kk = kb * 8 + rr;
                const int k = k0 + kk;
                Ms[kk][i] = (k < DIM) ? M[(size_t)k * DPAD + i0 + i] : 0.f;
            }
        }
        __syncthreads();
#pragma unroll
        for (int kk = 0; kk < 32; ++kk) {
            const float4 a = *reinterpret_cast<const float4*>(&Ft[kk][ty * 4]);
            const float4 b = *reinterpret_cast<const float4*>(&Ms[kk][tx * 4]);
            acc[0][0] += a.x * b.x; acc[0][1] += a.x * b.y;
            acc[0][2] += a.x * b.z; acc[0][3] += a.x * b.w;
            acc[1][0] += a.y * b.x; acc[1][1] += a.y * b.y;
            acc[1][2] += a.y * b.z; acc[1][3] += a.y * b.w;
            acc[2][0] += a.z * b.x; acc[2][1] += a.z * b.y;
            acc[2][2] += a.z * b.z; acc[2][3] += a.z * b.w;
            acc[3][0] += a.w * b.x; acc[3][1] += a.w * b.y;
            acc[3][2] += a.w * b.z; acc[3][3] += a.w * b.w;
        }
    }

#pragma unroll
    for (int r = 0; r < 4; ++r) {
        const int n = n0 + ty * 4 + r;
#pragma unroll
        for (int c = 0; c < 4; ++c) {
            const int i = i0 + tx * 4 + c;
            if (i < DIM) out[(size_t)n * DIM + i] = acc[r][c];
        }
    }
}

extern "C" void kernel_launch(void* const* d_in, const int* in_sizes, int n_in,
                              void* d_out, int out_size, void* d_ws, size_t ws_size,
                              hipStream_t stream) {
    const float* F  = (const float*)d_in[0];   // (1024, 680)
    const float* D  = (const float*)d_in[1];   // (48, 24, 48, 680)
    const float* qw = (const float*)d_in[2];   // (24,)
    float* out = (float*)d_out;
    char*  ws  = (char*)d_ws;

    uint4* awt = (uint4*)ws;                                    // 81.0 MiB bf16
    const size_t awt_bytes = (size_t)NCH * DPAD * 64 * 2;       // 84,934,656
    uint2* parts = (uint2*)(ws + awt_bytes);                    // 54.0 MiB bf16
    const size_t parts_bytes = (size_t)SPLITS * NTILE * 65536 * 2;  // 56,623,104
    float* M = (float*)(ws + awt_bytes + parts_bytes);          // 2.25 MiB fp32

    k1_transpose<<<dim3(NCH / 4, DPAD / 64), 256, 0, stream>>>(D, qw, awt);
    k2_gram<<<dim3(SPLITS, NTILE), 512, 0, stream>>>(awt, parts);
    k2_reduce<<<dim3(32, NTILE), 256, 0, stream>>>(parts, M);
    k3_out<<<dim3(16, 11), 256, 0, stream>>>(F, M, out);
}

// Round 4
// 426.832 us; speedup vs baseline: 1.1894x; 1.1894x over previous
//
#include <hip/hip_runtime.h>
#include <stdint.h>

#define DIM    680
#define DPAD   768      // 3 x 256 tiles
#define NCH    864      // 55296 / 64 g-chunks
#define NB_Q   24
#define SPLITS 72
#define STAGES 12       // NCH / SPLITS
#define NTILE  6        // upper-triangle 256x256 tiles of 3x3

typedef __bf16 bf16x8 __attribute__((ext_vector_type(8)));
typedef float  f32x16 __attribute__((ext_vector_type(16)));

typedef __attribute__((address_space(3))) unsigned       lds_u32;
typedef __attribute__((address_space(1))) const unsigned glb_u32;

__constant__ int c_tj[NTILE] = {0, 0, 0, 1, 1, 2};
__constant__ int c_ti[NTILE] = {0, 1, 2, 1, 2, 2};

static __device__ __forceinline__ unsigned f2bf(float x) {
    union { float f; unsigned u; } c; c.f = x;
    unsigned u = c.u;
    return (u + 0x7FFFu + ((u >> 16) & 1u)) >> 16;  // RNE
}

static __device__ __forceinline__ float bf2f(unsigned short h) {
    union { unsigned u; float f; } c; c.u = ((unsigned)h) << 16;
    return c.f;
}

// ---------------------------------------------------------------------------
// k1: D (55296 x 680 fp32) -> Awt bf16, scaled by sqrt(qw[b]), chunk-transposed:
//     16B slot (chunk cg, col i, kc) at uint4 index ((cg*768 + i)*8 + (kc ^ (i&7)))
//     holding g = cg*64 + kc*8 + 0..7 of column i.  Cols 680..767 zero-padded.
//     4 chunks per block, register-prefetch pipelined over the pack phase.
// ---------------------------------------------------------------------------
__global__ __launch_bounds__(256) void k1_transpose(
        const float* __restrict__ D, const float* __restrict__ qw,
        uint4* __restrict__ awt) {
    __shared__ float sq[NB_Q];
    __shared__ float tile[64][65];
    const int t   = threadIdx.x;
    const int cg0 = blockIdx.x * 4;
    const int i0  = blockIdx.y * 64;
    if (t < NB_Q) sq[t] = sqrtf(qw[t]);

    const int rb   = t >> 4;
    const int c4   = (t & 15) * 4;
    const int colg = i0 + c4;
    const int pc   = (t + 256) >> 3;   // pack-phase col for s=1
    const int c0   = t >> 3;           // pack-phase col for s=0
    const int kc   = t & 7;

    float4 v[4];
#pragma unroll
    for (int j = 0; j < 4; ++j) {
        const int g = cg0 * 64 + rb + j * 16;
        if (colg + 3 < DIM) {
            v[j] = *reinterpret_cast<const float4*>(D + (size_t)g * DIM + colg);
        } else {
            v[j].x = (colg + 0 < DIM) ? D[(size_t)g * DIM + colg + 0] : 0.f;
            v[j].y = (colg + 1 < DIM) ? D[(size_t)g * DIM + colg + 1] : 0.f;
            v[j].z = (colg + 2 < DIM) ? D[(size_t)g * DIM + colg + 2] : 0.f;
            v[j].w = (colg + 3 < DIM) ? D[(size_t)g * DIM + colg + 3] : 0.f;
        }
    }
    __syncthreads();   // sq ready; harmless for tile

#pragma unroll
    for (int cc = 0; cc < 4; ++cc) {
        const int cg = cg0 + cc;
        const int g0 = cg * 64;
#pragma unroll
        for (int j = 0; j < 4; ++j) {
            const int r = rb + j * 16;
            const float w = sq[((g0 + r) / 48) % 24];
            tile[r][c4 + 0] = v[j].x * w;
            tile[r][c4 + 1] = v[j].y * w;
            tile[r][c4 + 2] = v[j].z * w;
            tile[r][c4 + 3] = v[j].w * w;
        }
        __syncthreads();
        if (cc < 3) {   // prefetch next chunk while this one is packed
#pragma unroll
            for (int j = 0; j < 4; ++j) {
                const int g = (cg + 1) * 64 + rb + j * 16;
                if (colg + 3 < DIM) {
                    v[j] = *reinterpret_cast<const float4*>(D + (size_t)g * DIM + colg);
                } else {
                    v[j].x = (colg + 0 < DIM) ? D[(size_t)g * DIM + colg + 0] : 0.f;
                    v[j].y = (colg + 1 < DIM) ? D[(size_t)g * DIM + colg + 1] : 0.f;
                    v[j].z = (colg + 2 < DIM) ? D[(size_t)g * DIM + colg + 2] : 0.f;
                    v[j].w = (colg + 3 < DIM) ? D[(size_t)g * DIM + colg + 3] : 0.f;
                }
            }
        }
#pragma unroll
        for (int s = 0; s < 2; ++s) {
            const int c = s ? pc : c0;
            uint4 o;
            o.x = f2bf(tile[kc * 8 + 0][c]) | (f2bf(tile[kc * 8 + 1][c]) << 16);
            o.y = f2bf(tile[kc * 8 + 2][c]) | (f2bf(tile[kc * 8 + 3][c]) << 16);
            o.z = f2bf(tile[kc * 8 + 4][c]) | (f2bf(tile[kc * 8 + 5][c]) << 16);
            o.w = f2bf(tile[kc * 8 + 6][c]) | (f2bf(tile[kc * 8 + 7][c]) << 16);
            const size_t slot = ((size_t)cg * DPAD + (size_t)(i0 + c)) * 8
                              + (size_t)(kc ^ (c & 7));
            awt[slot] = o;
        }
        __syncthreads();
    }
}

// ---------------------------------------------------------------------------
// k2: partial[split][tile] = sum over this split's 12 chunks of
//     A_band(tj)^T * A_band(ti), upper-triangle tiles only (M symmetric).
//     grid (72 splits, 6 tiles), 512 threads = 8 waves (4 m x 2 n),
//     wave tile 64x128, mfma_f32_32x32x16_bf16.
//     m97-style staging: global_load_lds width=16 (direct HBM/L2 -> LDS DMA),
//     issue -> barrier -> compute -> barrier. No VGPR staging round-trip.
// ---------------------------------------------------------------------------
__global__ __launch_bounds__(512) void k2_gram(const uint4* __restrict__ awt,
                                               uint2* __restrict__ parts) {
    __shared__ uint4 smA[2048];   // 256 cols x 8 slots (swizzled), 32 KB
    __shared__ uint4 smB[2048];
    const int t     = threadIdx.x;
    const int split = blockIdx.x;
    const int t6    = blockIdx.y;
    const int tj    = c_tj[t6];   // row band of M
    const int ti    = c_ti[t6];   // col band of M
    const int wave  = t >> 6;
    const int lane  = t & 63;
    const int wm    = wave & 3;   // m: 64-row band
    const int wn    = wave >> 2;  // n: 128-col band
    const int cl    = lane & 31;
    const int half  = lane >> 5;

    f32x16 acc[2][4];
    const f32x16 zero = {};
#pragma unroll
    for (int a = 0; a < 2; ++a)
#pragma unroll
        for (int b = 0; b < 4; ++b) acc[a][b] = zero;

    for (int st = 0; st < STAGES; ++st) {
        const int cg = split * STAGES + st;
        const size_t bA = ((size_t)cg * DPAD + tj * 256) * 8;
        const size_t bB = ((size_t)cg * DPAD + ti * 256) * 8;
        // async direct-to-LDS staging (wave-uniform base + lane*16 layout)
#pragma unroll
        for (int j = 0; j < 4; ++j) {
            __builtin_amdgcn_global_load_lds(
                (glb_u32*)(awt + bA + j * 512 + t),
                (lds_u32*)(&smA[j * 512 + t]), 16, 0, 0);
            __builtin_amdgcn_global_load_lds(
                (glb_u32*)(awt + bB + j * 512 + t),
                (lds_u32*)(&smB[j * 512 + t]), 16, 0, 0);
        }
        __syncthreads();   // drains vmcnt -> LDS tiles ready

        const bf16x8* pA = reinterpret_cast<const bf16x8*>(smA);
        const bf16x8* pB = reinterpret_cast<const bf16x8*>(smB);
#pragma unroll
        for (int t4 = 0; t4 < 4; ++t4) {          // K = 64 per stage, 16/mfma
            const int kc = 2 * t4 + half;
            bf16x8 af[2], bfr[4];
#pragma unroll
            for (int ms = 0; ms < 2; ++ms) {
                const int col = wm * 64 + ms * 32 + cl;
                af[ms] = pA[col * 8 + (kc ^ (col & 7))];
            }
#pragma unroll
            for (int ns = 0; ns < 4; ++ns) {
                const int col = wn * 128 + ns * 32 + cl;
                bfr[ns] = pB[col * 8 + (kc ^ (col & 7))];
            }
#pragma unroll
            for (int ms = 0; ms < 2; ++ms)
#pragma unroll
                for (int ns = 0; ns < 4; ++ns)
                    acc[ms][ns] = __builtin_amdgcn_mfma_f32_32x32x16_bf16(
                        af[ms], bfr[ns], acc[ms][ns], 0, 0, 0);
        }
        __syncthreads();   // protect LDS before next stage's DMA writes
    }

    // row-quad packed bf16 stores: full-line coalesced, no atomics
    uint2* pt = parts + (size_t)(split * NTILE + t6) * 16384;
#pragma unroll
    for (int ms = 0; ms < 2; ++ms) {
        const int rowb = wm * 64 + ms * 32 + 4 * half;   // multiple of 4
#pragma unroll
        for (int ns = 0; ns < 4; ++ns) {
            const int colt = wn * 128 + ns * 32 + cl;
#pragma unroll
            for (int q = 0; q < 4; ++q) {                // rows rowb+8q .. +3
                uint2 w;
                w.x = f2bf(acc[ms][ns][q * 4 + 0]) | (f2bf(acc[ms][ns][q * 4 + 1]) << 16);
                w.y = f2bf(acc[ms][ns][q * 4 + 2]) | (f2bf(acc[ms][ns][q * 4 + 3]) << 16);
                pt[(size_t)(((rowb >> 2) + 2 * q) * 256 + colt)] = w;
            }
        }
    }
}

// ---------------------------------------------------------------------------
// k2r: M[768x768 fp32] = sum over 72 split-partials per tile, + mirror.
//     Tile layout: u64 word w = quad*256 + col -> rows 4*quad..+3 of col.
//     grid (32, 6), 256 threads, uint4 (2 words = 2 cols x 4 rows) per thread.
// ---------------------------------------------------------------------------
__global__ __launch_bounds__(256) void k2_reduce(
        const uint2* __restrict__ parts, float* __restrict__ M) {
    const int t6 = blockIdx.y;
    const int tj = c_tj[t6];
    const int ti = c_ti[t6];
    const int idx4 = blockIdx.x * 256 + threadIdx.x;   // uint4 index, 8192/tile
    const int w0 = idx4 * 2;
    const int quad = w0 >> 8;
    const int c = w0 & 255;                            // even
    float s[8] = {0.f, 0.f, 0.f, 0.f, 0.f, 0.f, 0.f, 0.f};
    const uint4* base = reinterpret_cast<const uint4*>(parts) + idx4;
#pragma unroll 8
    for (int sp = 0; sp < SPLITS; ++sp) {
        const uint4 u = base[(size_t)(sp * NTILE + t6) * 8192];
        s[0] += bf2f((unsigned short)(u.x & 0xFFFF));
        s[1] += bf2f((unsigned short)(u.x >> 16));
        s[2] += bf2f((unsigned short)(u.y & 0xFFFF));
        s[3] += bf2f((unsigned short)(u.y >> 16));
        s[4] += bf2f((unsigned short)(u.z & 0xFFFF));
        s[5] += bf2f((unsigned short)(u.z >> 16));
        s[6] += bf2f((unsigned short)(u.w & 0xFFFF));
        s[7] += bf2f((unsigned short)(u.w >> 16));
    }
    const int R = tj * 256 + 4 * quad;
    const int C = ti * 256 + c;
#pragma unroll
    for (int i = 0; i < 4; ++i) {
        float2 d = {s[i], s[4 + i]};
        *reinterpret_cast<float2*>(M + (size_t)(R + i) * DPAD + C) = d;
    }
    if (ti != tj) {
        float4 m0 = {s[0], s[1], s[2], s[3]};
        float4 m1 = {s[4], s[5], s[6], s[7]};
        *reinterpret_cast<float4*>(M + (size_t)(C + 0) * DPAD + R) = m0;
        *reinterpret_cast<float4*>(M + (size_t)(C + 1) * DPAD + R) = m1;
    }
}

// ---------------------------------------------------------------------------
// k3: out(1024x680) = F(1024x680) @ M(768-stride).
//     fp32 tiled GEMM, 64x64 tile / block, 256 threads, 4x4 per thread.
// ---------------------------------------------------------------------------
__global__ __launch_bounds__(256) void k3_out(const float* __restrict__ F,
                                              const float* __restrict__ M,
                                              float* __restrict__ out) {
    __shared__ float Ft[32][68];   // [k][n]
    __shared__ float Ms[32][68];   // [k][i]
    const int t  = threadIdx.x;
    const int tx = t & 15;
    const int ty = t >> 4;
    const int n0 = blockIdx.x * 64;
    const int i0 = blockIdx.y * 64;
    float acc[4][4] = {};

    for (int k0 = 0; k0 < DIM; k0 += 32) {
        __syncthreads();
        {
            const int kk = t & 31;
            const int nb = t >> 5;
#pragma unroll
            for (int rr = 0; rr < 8; ++rr) {
                const int n = nb * 8 + rr;
                const int k = k0 + kk;
                Ft[kk][n] = (k < DIM) ? F[(size_t)(n0 + n) * DIM + k] : 0.f;
            }
        }
        {
            const int i  = t & 63;
            const int kb = t >> 6;
#pragma unroll
            for (int rr = 0; rr < 8; ++rr) {
                const int kk = kb * 8 + rr;
                const int k = k0 + kk;
                Ms[kk][i] = (k < DIM) ? M[(size_t)k * DPAD + i0 + i] : 0.f;
            }
        }
        __syncthreads();
#pragma unroll
        for (int kk = 0; kk < 32; ++kk) {
            const float4 a = *reinterpret_cast<const float4*>(&Ft[kk][ty * 4]);
            const float4 b = *reinterpret_cast<const float4*>(&Ms[kk][tx * 4]);
            acc[0][0] += a.x * b.x; acc[0][1] += a.x * b.y;
            acc[0][2] += a.x * b.z; acc[0][3] += a.x * b.w;
            acc[1][0] += a.y * b.x; acc[1][1] += a.y * b.y;
            acc[1][2] += a.y * b.z; acc[1][3] += a.y * b.w;
            acc[2][0] += a.z * b.x; acc[2][1] += a.z * b.y;
            acc[2][2] += a.z * b.z; acc[2][3] += a.z * b.w;
            acc[3][0] += a.w * b.x; acc[3][1] += a.w * b.y;
            acc[3][2] += a.w * b.z; acc[3][3] += a.w * b.w;
        }
    }

#pragma unroll
    for (int r = 0; r < 4; ++r) {
        const int n = n0 + ty * 4 + r;
#pragma unroll
        for (int c = 0; c < 4; ++c) {
            const int i = i0 + tx * 4 + c;
            if (i < DIM) out[(size_t)n * DIM + i] = acc[r][c];
        }
    }
}

extern "C" void kernel_launch(void* const* d_in, const int* in_sizes, int n_in,
                              void* d_out, int out_size, void* d_ws, size_t ws_size,
                              hipStream_t stream) {
    const float* F  = (const float*)d_in[0];   // (1024, 680)
    const float* D  = (const float*)d_in[1];   // (48, 24, 48, 680)
    const float* qw = (const float*)d_in[2];   // (24,)
    float* out = (float*)d_out;
    char*  ws  = (char*)d_ws;

    uint4* awt = (uint4*)ws;                                    // 81.0 MiB bf16
    const size_t awt_bytes = (size_t)NCH * DPAD * 64 * 2;       // 84,934,656
    uint2* parts = (uint2*)(ws + awt_bytes);                    // 54.0 MiB bf16
    const size_t parts_bytes = (size_t)SPLITS * NTILE * 65536 * 2;  // 56,623,104
    float* M = (float*)(ws + awt_bytes + parts_bytes);          // 2.25 MiB fp32

    k1_transpose<<<dim3(NCH / 4, DPAD / 64), 256, 0, stream>>>(D, qw, awt);
    k2_gram<<<dim3(SPLITS, NTILE), 512, 0, stream>>>(awt, parts);
    k2_reduce<<<dim3(32, NTILE), 256, 0, stream>>>(parts, M);
    k3_out<<<dim3(16, 11), 256, 0, stream>>>(F, M, out);
}

// Round 5
// 354.535 us; speedup vs baseline: 1.4319x; 1.2039x over previous
//
#include <hip/hip_runtime.h>
#include <stdint.h>

#define DIM    680
#define DPAD   768      // 3 x 256 tiles
#define NCH    864      // 55296 / 64 g-chunks
#define NB_Q   24
#define SPLITS 72
#define STAGES 12       // NCH / SPLITS
#define NTILE  6        // upper-triangle 256x256 tiles of 3x3
#define KSLICE 4        // k3 split-K factor (680 = 4 x 170)
#define KLEN   170

typedef __bf16 bf16x8 __attribute__((ext_vector_type(8)));
typedef float  f32x16 __attribute__((ext_vector_type(16)));

typedef __attribute__((address_space(3))) unsigned       lds_u32;
typedef __attribute__((address_space(1))) const unsigned glb_u32;

__constant__ int c_tj[NTILE] = {0, 0, 0, 1, 1, 2};
__constant__ int c_ti[NTILE] = {0, 1, 2, 1, 2, 2};

static __device__ __forceinline__ unsigned f2bf(float x) {
    union { float f; unsigned u; } c; c.f = x;
    unsigned u = c.u;
    return (u + 0x7FFFu + ((u >> 16) & 1u)) >> 16;  // RNE
}

static __device__ __forceinline__ float bf2f(unsigned short h) {
    union { unsigned u; float f; } c; c.u = ((unsigned)h) << 16;
    return c.f;
}

// ---------------------------------------------------------------------------
// k1: D (55296 x 680 fp32) -> Awt bf16, scaled by sqrt(qw[b]), chunk-transposed:
//     16B slot (chunk cg, col i, kc) at uint4 index ((cg*768 + i)*8 + (kc ^ (i&7)))
//     holding g = cg*64 + kc*8 + 0..7 of column i.  Cols 680..767 zero-padded.
//     4 chunks per block, register-prefetch pipelined over the pack phase.
// ---------------------------------------------------------------------------
__global__ __launch_bounds__(256) void k1_transpose(
        const float* __restrict__ D, const float* __restrict__ qw,
        uint4* __restrict__ awt) {
    __shared__ float sq[NB_Q];
    __shared__ float tile[64][65];
    const int t   = threadIdx.x;
    const int cg0 = blockIdx.x * 4;
    const int i0  = blockIdx.y * 64;
    if (t < NB_Q) sq[t] = sqrtf(qw[t]);

    const int rb   = t >> 4;
    const int c4   = (t & 15) * 4;
    const int colg = i0 + c4;
    const int pc   = (t + 256) >> 3;   // pack-phase col for s=1
    const int c0   = t >> 3;           // pack-phase col for s=0
    const int kc   = t & 7;

    float4 v[4];
#pragma unroll
    for (int j = 0; j < 4; ++j) {
        const int g = cg0 * 64 + rb + j * 16;
        if (colg + 3 < DIM) {
            v[j] = *reinterpret_cast<const float4*>(D + (size_t)g * DIM + colg);
        } else {
            v[j].x = (colg + 0 < DIM) ? D[(size_t)g * DIM + colg + 0] : 0.f;
            v[j].y = (colg + 1 < DIM) ? D[(size_t)g * DIM + colg + 1] : 0.f;
            v[j].z = (colg + 2 < DIM) ? D[(size_t)g * DIM + colg + 2] : 0.f;
            v[j].w = (colg + 3 < DIM) ? D[(size_t)g * DIM + colg + 3] : 0.f;
        }
    }
    __syncthreads();   // sq ready; harmless for tile

#pragma unroll
    for (int cc = 0; cc < 4; ++cc) {
        const int cg = cg0 + cc;
        const int g0 = cg * 64;
#pragma unroll
        for (int j = 0; j < 4; ++j) {
            const int r = rb + j * 16;
            const float w = sq[((g0 + r) / 48) % 24];
            tile[r][c4 + 0] = v[j].x * w;
            tile[r][c4 + 1] = v[j].y * w;
            tile[r][c4 + 2] = v[j].z * w;
            tile[r][c4 + 3] = v[j].w * w;
        }
        __syncthreads();
        if (cc < 3) {   // prefetch next chunk while this one is packed
#pragma unroll
            for (int j = 0; j < 4; ++j) {
                const int g = (cg + 1) * 64 + rb + j * 16;
                if (colg + 3 < DIM) {
                    v[j] = *reinterpret_cast<const float4*>(D + (size_t)g * DIM + colg);
                } else {
                    v[j].x = (colg + 0 < DIM) ? D[(size_t)g * DIM + colg + 0] : 0.f;
                    v[j].y = (colg + 1 < DIM) ? D[(size_t)g * DIM + colg + 1] : 0.f;
                    v[j].z = (colg + 2 < DIM) ? D[(size_t)g * DIM + colg + 2] : 0.f;
                    v[j].w = (colg + 3 < DIM) ? D[(size_t)g * DIM + colg + 3] : 0.f;
                }
            }
        }
#pragma unroll
        for (int s = 0; s < 2; ++s) {
            const int c = s ? pc : c0;
            uint4 o;
            o.x = f2bf(tile[kc * 8 + 0][c]) | (f2bf(tile[kc * 8 + 1][c]) << 16);
            o.y = f2bf(tile[kc * 8 + 2][c]) | (f2bf(tile[kc * 8 + 3][c]) << 16);
            o.z = f2bf(tile[kc * 8 + 4][c]) | (f2bf(tile[kc * 8 + 5][c]) << 16);
            o.w = f2bf(tile[kc * 8 + 6][c]) | (f2bf(tile[kc * 8 + 7][c]) << 16);
            const size_t slot = ((size_t)cg * DPAD + (size_t)(i0 + c)) * 8
                              + (size_t)(kc ^ (c & 7));
            awt[slot] = o;
        }
        __syncthreads();
    }
}

// ---------------------------------------------------------------------------
// k2: partial[split][tile] = sum over this split's 12 chunks of
//     A_band(tj)^T * A_band(ti), upper-triangle tiles only (M symmetric).
//     grid (72 splits, 6 tiles), 512 threads = 8 waves (4 m x 2 n),
//     wave tile 64x128, mfma_f32_32x32x16_bf16.
//     m97-style staging: global_load_lds width=16 (direct HBM/L2 -> LDS DMA),
//     issue -> barrier -> compute -> barrier. No VGPR staging round-trip.
// ---------------------------------------------------------------------------
__global__ __launch_bounds__(512) void k2_gram(const uint4* __restrict__ awt,
                                               uint2* __restrict__ parts) {
    __shared__ uint4 smA[2048];   // 256 cols x 8 slots (swizzled), 32 KB
    __shared__ uint4 smB[2048];
    const int t     = threadIdx.x;
    const int split = blockIdx.x;
    const int t6    = blockIdx.y;
    const int tj    = c_tj[t6];   // row band of M
    const int ti    = c_ti[t6];   // col band of M
    const int wave  = t >> 6;
    const int lane  = t & 63;
    const int wm    = wave & 3;   // m: 64-row band
    const int wn    = wave >> 2;  // n: 128-col band
    const int cl    = lane & 31;
    const int half  = lane >> 5;

    f32x16 acc[2][4];
    const f32x16 zero = {};
#pragma unroll
    for (int a = 0; a < 2; ++a)
#pragma unroll
        for (int b = 0; b < 4; ++b) acc[a][b] = zero;

    for (int st = 0; st < STAGES; ++st) {
        const int cg = split * STAGES + st;
        const size_t bA = ((size_t)cg * DPAD + tj * 256) * 8;
        const size_t bB = ((size_t)cg * DPAD + ti * 256) * 8;
        // async direct-to-LDS staging (wave-uniform base + lane*16 layout)
#pragma unroll
        for (int j = 0; j < 4; ++j) {
            __builtin_amdgcn_global_load_lds(
                (glb_u32*)(awt + bA + j * 512 + t),
                (lds_u32*)(&smA[j * 512 + t]), 16, 0, 0);
            __builtin_amdgcn_global_load_lds(
                (glb_u32*)(awt + bB + j * 512 + t),
                (lds_u32*)(&smB[j * 512 + t]), 16, 0, 0);
        }
        __syncthreads();   // drains vmcnt -> LDS tiles ready

        const bf16x8* pA = reinterpret_cast<const bf16x8*>(smA);
        const bf16x8* pB = reinterpret_cast<const bf16x8*>(smB);
#pragma unroll
        for (int t4 = 0; t4 < 4; ++t4) {          // K = 64 per stage, 16/mfma
            const int kc = 2 * t4 + half;
            bf16x8 af[2], bfr[4];
#pragma unroll
            for (int ms = 0; ms < 2; ++ms) {
                const int col = wm * 64 + ms * 32 + cl;
                af[ms] = pA[col * 8 + (kc ^ (col & 7))];
            }
#pragma unroll
            for (int ns = 0; ns < 4; ++ns) {
                const int col = wn * 128 + ns * 32 + cl;
                bfr[ns] = pB[col * 8 + (kc ^ (col & 7))];
            }
#pragma unroll
            for (int ms = 0; ms < 2; ++ms)
#pragma unroll
                for (int ns = 0; ns < 4; ++ns)
                    acc[ms][ns] = __builtin_amdgcn_mfma_f32_32x32x16_bf16(
                        af[ms], bfr[ns], acc[ms][ns], 0, 0, 0);
        }
        __syncthreads();   // protect LDS before next stage's DMA writes
    }

    // row-quad packed bf16 stores: full-line coalesced, no atomics
    uint2* pt = parts + (size_t)(split * NTILE + t6) * 16384;
#pragma unroll
    for (int ms = 0; ms < 2; ++ms) {
        const int rowb = wm * 64 + ms * 32 + 4 * half;   // multiple of 4
#pragma unroll
        for (int ns = 0; ns < 4; ++ns) {
            const int colt = wn * 128 + ns * 32 + cl;
#pragma unroll
            for (int q = 0; q < 4; ++q) {                // rows rowb+8q .. +3
                uint2 w;
                w.x = f2bf(acc[ms][ns][q * 4 + 0]) | (f2bf(acc[ms][ns][q * 4 + 1]) << 16);
                w.y = f2bf(acc[ms][ns][q * 4 + 2]) | (f2bf(acc[ms][ns][q * 4 + 3]) << 16);
                pt[(size_t)(((rowb >> 2) + 2 * q) * 256 + colt)] = w;
            }
        }
    }
}

// ---------------------------------------------------------------------------
// k2r: M[768x768 fp32] = sum over 72 split-partials per tile, + mirror.
//     Tile layout: u64 word w = quad*256 + col -> rows 4*quad..+3 of col.
//     grid (32, 6), 256 threads, uint4 (2 words = 2 cols x 4 rows) per thread.
// ---------------------------------------------------------------------------
__global__ __launch_bounds__(256) void k2_reduce(
        const uint2* __restrict__ parts, float* __restrict__ M) {
    const int t6 = blockIdx.y;
    const int tj = c_tj[t6];
    const int ti = c_ti[t6];
    const int idx4 = blockIdx.x * 256 + threadIdx.x;   // uint4 index, 8192/tile
    const int w0 = idx4 * 2;
    const int quad = w0 >> 8;
    const int c = w0 & 255;                            // even
    float s[8] = {0.f, 0.f, 0.f, 0.f, 0.f, 0.f, 0.f, 0.f};
    const uint4* base = reinterpret_cast<const uint4*>(parts) + idx4;
#pragma unroll 8
    for (int sp = 0; sp < SPLITS; ++sp) {
        const uint4 u = base[(size_t)(sp * NTILE + t6) * 8192];
        s[0] += bf2f((unsigned short)(u.x & 0xFFFF));
        s[1] += bf2f((unsigned short)(u.x >> 16));
        s[2] += bf2f((unsigned short)(u.y & 0xFFFF));
        s[3] += bf2f((unsigned short)(u.y >> 16));
        s[4] += bf2f((unsigned short)(u.z & 0xFFFF));
        s[5] += bf2f((unsigned short)(u.z >> 16));
        s[6] += bf2f((unsigned short)(u.w & 0xFFFF));
        s[7] += bf2f((unsigned short)(u.w >> 16));
    }
    const int R = tj * 256 + 4 * quad;
    const int C = ti * 256 + c;
#pragma unroll
    for (int i = 0; i < 4; ++i) {
        float2 d = {s[i], s[4 + i]};
        *reinterpret_cast<float2*>(M + (size_t)(R + i) * DPAD + C) = d;
    }
    if (ti != tj) {
        float4 m0 = {s[0], s[1], s[2], s[3]};
        float4 m1 = {s[4], s[5], s[6], s[7]};
        *reinterpret_cast<float4*>(M + (size_t)(C + 0) * DPAD + R) = m0;
        *reinterpret_cast<float4*>(M + (size_t)(C + 1) * DPAD + R) = m1;
    }
}

// ---------------------------------------------------------------------------
// k3: outp[ks](1024x680) = F(:, ks-slice) @ M(ks-slice, :), split-K over 4
//     slices of 170. fp32 tiled GEMM, 64x64 tile, 256 threads, 4x4/thread.
//     grid (16, 11, 4) = 704 blocks (vs 176 unsplit: was latency-starved).
// ---------------------------------------------------------------------------
__global__ __launch_bounds__(256) void k3_out(const float* __restrict__ F,
                                              const float* __restrict__ M,
                                              float* __restrict__ outp) {
    __shared__ float Ft[32][68];   // [k][n]
    __shared__ float Ms[32][68];   // [k][i]
    const int t  = threadIdx.x;
    const int tx = t & 15;
    const int ty = t >> 4;
    const int n0 = blockIdx.x * 64;
    const int i0 = blockIdx.y * 64;
    const int ks = blockIdx.z;
    const int kbeg = ks * KLEN;
    const int kend = kbeg + KLEN;
    float acc[4][4] = {};

    for (int k0 = kbeg; k0 < kend; k0 += 32) {
        __syncthreads();
        {
            const int kk = t & 31;
            const int nb = t >> 5;
            const int k = k0 + kk;
#pragma unroll
            for (int rr = 0; rr < 8; ++rr) {
                const int n = nb * 8 + rr;
                Ft[kk][n] = (k < kend) ? F[(size_t)(n0 + n) * DIM + k] : 0.f;
            }
        }
        {
            const int i  = t & 63;
            const int kb = t >> 6;
#pragma unroll
            for (int rr = 0; rr < 8; ++rr) {
                const int kk = kb * 8 + rr;
                const int k = k0 + kk;
                Ms[kk][i] = (k < kend) ? M[(size_t)k * DPAD + i0 + i] : 0.f;
            }
        }
        __syncthreads();
#pragma unroll
        for (int kk = 0; kk < 32; ++kk) {
            const float4 a = *reinterpret_cast<const float4*>(&Ft[kk][ty * 4]);
            const float4 b = *reinterpret_cast<const float4*>(&Ms[kk][tx * 4]);
            acc[0][0] += a.x * b.x; acc[0][1] += a.x * b.y;
            acc[0][2] += a.x * b.z; acc[0][3] += a.x * b.w;
            acc[1][0] += a.y * b.x; acc[1][1] += a.y * b.y;
            acc[1][2] += a.y * b.z; acc[1][3] += a.y * b.w;
            acc[2][0] += a.z * b.x; acc[2][1] += a.z * b.y;
            acc[2][2] += a.z * b.z; acc[2][3] += a.z * b.w;
            acc[3][0] += a.w * b.x; acc[3][1] += a.w * b.y;
            acc[3][2] += a.w * b.z; acc[3][3] += a.w * b.w;
        }
    }

    float* op = outp + (size_t)ks * ((size_t)1024 * DIM);
#pragma unroll
    for (int r = 0; r < 4; ++r) {
        const int n = n0 + ty * 4 + r;
#pragma unroll
        for (int c = 0; c < 4; ++c) {
            const int i = i0 + tx * 4 + c;
            if (i < DIM) op[(size_t)n * DIM + i] = acc[r][c];
        }
    }
}

// ---------------------------------------------------------------------------
// k3r: out = sum of 4 K-slice partials. 680 blocks x 256 threads x float4.
// ---------------------------------------------------------------------------
__global__ __launch_bounds__(256) void k3_reduce(
        const float4* __restrict__ outp, float4* __restrict__ out) {
    const int idx = blockIdx.x * 256 + threadIdx.x;   // 174080 float4's
    const int N4 = 1024 * DIM / 4;
    const float4 a = outp[idx];
    const float4 b = outp[N4 + idx];
    const float4 c = outp[2 * N4 + idx];
    const float4 d = outp[3 * N4 + idx];
    float4 s;
    s.x = (a.x + b.x) + (c.x + d.x);
    s.y = (a.y + b.y) + (c.y + d.y);
    s.z = (a.z + b.z) + (c.z + d.z);
    s.w = (a.w + b.w) + (c.w + d.w);
    out[idx] = s;
}

extern "C" void kernel_launch(void* const* d_in, const int* in_sizes, int n_in,
                              void* d_out, int out_size, void* d_ws, size_t ws_size,
                              hipStream_t stream) {
    const float* F  = (const float*)d_in[0];   // (1024, 680)
    const float* D  = (const float*)d_in[1];   // (48, 24, 48, 680)
    const float* qw = (const float*)d_in[2];   // (24,)
    float* out = (float*)d_out;
    char*  ws  = (char*)d_ws;

    uint4* awt = (uint4*)ws;                                    // 81.0 MiB bf16
    const size_t awt_bytes = (size_t)NCH * DPAD * 64 * 2;       // 84,934,656
    uint2* parts = (uint2*)(ws + awt_bytes);                    // 54.0 MiB bf16
    const size_t parts_bytes = (size_t)SPLITS * NTILE * 65536 * 2;  // 56,623,104
    float* M = (float*)(ws + awt_bytes + parts_bytes);          // 2.25 MiB fp32
    // k3 partials alias awt (dead after k2_gram; stream-ordered): 11.14 MiB
    float* outp = (float*)ws;

    k1_transpose<<<dim3(NCH / 4, DPAD / 64), 256, 0, stream>>>(D, qw, awt);
    k2_gram<<<dim3(SPLITS, NTILE), 512, 0, stream>>>(awt, parts);
    k2_reduce<<<dim3(32, NTILE), 256, 0, stream>>>(parts, M);
    k3_out<<<dim3(16, 11, KSLICE), 256, 0, stream>>>(F, M, outp);
    k3_reduce<<<dim3(1024 * DIM / 4 / 256), 256, 0, stream>>>(
        (const float4*)outp, (float4*)out);
}

// Round 6
// 351.462 us; speedup vs baseline: 1.4444x; 1.0087x over previous
//
#include <hip/hip_runtime.h>
#include <stdint.h>

#define DIM    680
#define DPAD   768      // 3 x 256 tiles
#define NCH    864      // 55296 / 64 g-chunks
#define NB_Q   24
#define SPLITS 72
#define STAGES 12       // NCH / SPLITS
#define NTILE  6        // upper-triangle 256x256 tiles of 3x3
#define KSLICE 8        // k3 split-K factor (680 = 8 x 85)
#define KLEN   85

typedef __bf16 bf16x8 __attribute__((ext_vector_type(8)));
typedef float  f32x16 __attribute__((ext_vector_type(16)));

typedef __attribute__((address_space(3))) unsigned       lds_u32;
typedef __attribute__((address_space(1))) const unsigned glb_u32;

__constant__ int c_tj[NTILE] = {0, 0, 0, 1, 1, 2};
__constant__ int c_ti[NTILE] = {0, 1, 2, 1, 2, 2};

static __device__ __forceinline__ unsigned f2bf(float x) {
    union { float f; unsigned u; } c; c.f = x;
    unsigned u = c.u;
    return (u + 0x7FFFu + ((u >> 16) & 1u)) >> 16;  // RNE
}

static __device__ __forceinline__ float bf2f(unsigned short h) {
    union { unsigned u; float f; } c; c.u = ((unsigned)h) << 16;
    return c.f;
}

// ---------------------------------------------------------------------------
// k1-v2: D (55296 x 680 fp32) -> Awt bf16 (scaled by sqrt(qw[b])), chunk-
//     transposed for k2's DMA: 16B slot (cg, col i, kc) at uint4 index
//     ((cg*768 + i)*8 + (kc ^ (i&7))) holding g = cg*64 + kc*8 + 0..7 of col i.
//     Staging: global_load_lds width=16 of RAW fp32 (no VGPR round-trip).
//     Lane->colgroup XOR swizzle (sg = (t&15) ^ (row>>3)) makes the forced
//     lane-contiguous LDS layout 2-way-conflict-only for column gathers.
//     Cols >= 680 are pre-zeroed once (mask depends only on (t, rd)).
// ---------------------------------------------------------------------------
__global__ __launch_bounds__(256) void k1_transpose(
        const float* __restrict__ D, const float* __restrict__ qw,
        uint4* __restrict__ awt) {
    __shared__ float sq[NB_Q];
    __shared__ float tile[4096];   // 64 rows x 64 cols fp32, swizzled colgroups
    const int t   = threadIdx.x;
    const int cg0 = blockIdx.x * 4;
    const int i0  = blockIdx.y * 64;
    if (t < NB_Q) sq[t] = sqrtf(qw[t]);

    int  rowr[4], gcol[4];
    bool inb[4];
#pragma unroll
    for (int rd = 0; rd < 4; ++rd) {
        const int row = rd * 16 + (t >> 4);
        const int p   = row >> 3;
        const int sg  = (t & 15) ^ p;
        rowr[rd] = row;
        gcol[rd] = i0 + sg * 4;          // multiple of 4; 680%4==0 -> no straddle
        inb[rd]  = (gcol[rd] < DIM);
        if (!inb[rd]) {                  // zero once; OOB slots stay zero
            float4 z = {0.f, 0.f, 0.f, 0.f};
            *reinterpret_cast<float4*>(&tile[rd * 1024 + t * 4]) = z;
        }
    }
    __syncthreads();   // sq + zeros visible

    for (int cc = 0; cc < 4; ++cc) {
        const int cg = cg0 + cc;
        const int g0 = cg * 64;
#pragma unroll
        for (int rd = 0; rd < 4; ++rd) {
            if (inb[rd]) {
                __builtin_amdgcn_global_load_lds(
                    (glb_u32*)(D + (size_t)(g0 + rowr[rd]) * DIM + gcol[rd]),
                    (lds_u32*)(&tile[rd * 1024 + t * 4]), 16, 0, 0);
            }
        }
        __syncthreads();   // drains DMA

#pragma unroll
        for (int s = 0; s < 2; ++s) {
            const int l  = t + s * 256;
            const int c  = l >> 3;       // local col 0..63
            const int kc = l & 7;        // 16B chunk within col
            unsigned h[8];
#pragma unroll
            for (int j = 0; j < 8; ++j) {
                const int row = kc * 8 + j;
                const float v = tile[row * 64 + (((c >> 2) ^ kc) << 2) + (c & 3)];
                const int b = ((g0 + row) / 48) % 24;
                h[j] = f2bf(v * sq[b]);
            }
            uint4 o;
            o.x = h[0] | (h[1] << 16);
            o.y = h[2] | (h[3] << 16);
            o.z = h[4] | (h[5] << 16);
            o.w = h[6] | (h[7] << 16);
            const size_t slot = ((size_t)cg * DPAD + (size_t)(i0 + c)) * 8
                              + (size_t)(kc ^ (c & 7));
            awt[slot] = o;
        }
        __syncthreads();   // protect tile before next chunk's DMA
    }
}

// ---------------------------------------------------------------------------
// k2: partial[split][tile] = sum over this split's 12 chunks of
//     A_band(tj)^T * A_band(ti), upper-triangle tiles only (M symmetric).
//     grid (72 splits, 6 tiles), 512 threads = 8 waves (4 m x 2 n),
//     wave tile 64x128, mfma_f32_32x32x16_bf16.
//     m97-style staging: global_load_lds width=16, issue->barrier->compute.
// ---------------------------------------------------------------------------
__global__ __launch_bounds__(512) void k2_gram(const uint4* __restrict__ awt,
                                               uint2* __restrict__ parts) {
    __shared__ uint4 smA[2048];   // 256 cols x 8 slots (swizzled), 32 KB
    __shared__ uint4 smB[2048];
    const int t     = threadIdx.x;
    const int split = blockIdx.x;
    const int t6    = blockIdx.y;
    const int tj    = c_tj[t6];   // row band of M
    const int ti    = c_ti[t6];   // col band of M
    const int wave  = t >> 6;
    const int lane  = t & 63;
    const int wm    = wave & 3;   // m: 64-row band
    const int wn    = wave >> 2;  // n: 128-col band
    const int cl    = lane & 31;
    const int half  = lane >> 5;

    f32x16 acc[2][4];
    const f32x16 zero = {};
#pragma unroll
    for (int a = 0; a < 2; ++a)
#pragma unroll
        for (int b = 0; b < 4; ++b) acc[a][b] = zero;

    for (int st = 0; st < STAGES; ++st) {
        const int cg = split * STAGES + st;
        const size_t bA = ((size_t)cg * DPAD + tj * 256) * 8;
        const size_t bB = ((size_t)cg * DPAD + ti * 256) * 8;
#pragma unroll
        for (int j = 0; j < 4; ++j) {
            __builtin_amdgcn_global_load_lds(
                (glb_u32*)(awt + bA + j * 512 + t),
                (lds_u32*)(&smA[j * 512 + t]), 16, 0, 0);
            __builtin_amdgcn_global_load_lds(
                (glb_u32*)(awt + bB + j * 512 + t),
                (lds_u32*)(&smB[j * 512 + t]), 16, 0, 0);
        }
        __syncthreads();   // drains vmcnt -> LDS tiles ready

        const bf16x8* pA = reinterpret_cast<const bf16x8*>(smA);
        const bf16x8* pB = reinterpret_cast<const bf16x8*>(smB);
#pragma unroll
        for (int t4 = 0; t4 < 4; ++t4) {          // K = 64 per stage, 16/mfma
            const int kc = 2 * t4 + half;
            bf16x8 af[2], bfr[4];
#pragma unroll
            for (int ms = 0; ms < 2; ++ms) {
                const int col = wm * 64 + ms * 32 + cl;
                af[ms] = pA[col * 8 + (kc ^ (col & 7))];
            }
#pragma unroll
            for (int ns = 0; ns < 4; ++ns) {
                const int col = wn * 128 + ns * 32 + cl;
                bfr[ns] = pB[col * 8 + (kc ^ (col & 7))];
            }
#pragma unroll
            for (int ms = 0; ms < 2; ++ms)
#pragma unroll
                for (int ns = 0; ns < 4; ++ns)
                    acc[ms][ns] = __builtin_amdgcn_mfma_f32_32x32x16_bf16(
                        af[ms], bfr[ns], acc[ms][ns], 0, 0, 0);
        }
        __syncthreads();   // protect LDS before next stage's DMA writes
    }

    // row-quad packed bf16 stores: full-line coalesced, no atomics
    uint2* pt = parts + (size_t)(split * NTILE + t6) * 16384;
#pragma unroll
    for (int ms = 0; ms < 2; ++ms) {
        const int rowb = wm * 64 + ms * 32 + 4 * half;   // multiple of 4
#pragma unroll
        for (int ns = 0; ns < 4; ++ns) {
            const int colt = wn * 128 + ns * 32 + cl;
#pragma unroll
            for (int q = 0; q < 4; ++q) {                // rows rowb+8q .. +3
                uint2 w;
                w.x = f2bf(acc[ms][ns][q * 4 + 0]) | (f2bf(acc[ms][ns][q * 4 + 1]) << 16);
                w.y = f2bf(acc[ms][ns][q * 4 + 2]) | (f2bf(acc[ms][ns][q * 4 + 3]) << 16);
                pt[(size_t)(((rowb >> 2) + 2 * q) * 256 + colt)] = w;
            }
        }
    }
}

// ---------------------------------------------------------------------------
// k2r: M[768x768 fp32] = sum over 72 split-partials per tile, + mirror.
//     Tile layout: u64 word w = quad*256 + col -> rows 4*quad..+3 of col.
//     grid (32, 6), 256 threads, uint4 (2 words = 2 cols x 4 rows) per thread.
// ---------------------------------------------------------------------------
__global__ __launch_bounds__(256) void k2_reduce(
        const uint2* __restrict__ parts, float* __restrict__ M) {
    const int t6 = blockIdx.y;
    const int tj = c_tj[t6];
    const int ti = c_ti[t6];
    const int idx4 = blockIdx.x * 256 + threadIdx.x;   // uint4 index, 8192/tile
    const int w0 = idx4 * 2;
    const int quad = w0 >> 8;
    const int c = w0 & 255;                            // even
    float s[8] = {0.f, 0.f, 0.f, 0.f, 0.f, 0.f, 0.f, 0.f};
    const uint4* base = reinterpret_cast<const uint4*>(parts) + idx4;
#pragma unroll 8
    for (int sp = 0; sp < SPLITS; ++sp) {
        const uint4 u = base[(size_t)(sp * NTILE + t6) * 8192];
        s[0] += bf2f((unsigned short)(u.x & 0xFFFF));
        s[1] += bf2f((unsigned short)(u.x >> 16));
        s[2] += bf2f((unsigned short)(u.y & 0xFFFF));
        s[3] += bf2f((unsigned short)(u.y >> 16));
        s[4] += bf2f((unsigned short)(u.z & 0xFFFF));
        s[5] += bf2f((unsigned short)(u.z >> 16));
        s[6] += bf2f((unsigned short)(u.w & 0xFFFF));
        s[7] += bf2f((unsigned short)(u.w >> 16));
    }
    const int R = tj * 256 + 4 * quad;
    const int C = ti * 256 + c;
#pragma unroll
    for (int i = 0; i < 4; ++i) {
        float2 d = {s[i], s[4 + i]};
        *reinterpret_cast<float2*>(M + (size_t)(R + i) * DPAD + C) = d;
    }
    if (ti != tj) {
        float4 m0 = {s[0], s[1], s[2], s[3]};
        float4 m1 = {s[4], s[5], s[6], s[7]};
        *reinterpret_cast<float4*>(M + (size_t)(C + 0) * DPAD + R) = m0;
        *reinterpret_cast<float4*>(M + (size_t)(C + 1) * DPAD + R) = m1;
    }
}

// ---------------------------------------------------------------------------
// k3: outp[ks](1024x680) = F(:, ks-slice) @ M(ks-slice, :), split-K over 8
//     slices of 85. fp32 tiled GEMM, 64x64 tile, 256 threads, 4x4/thread.
//     grid (16, 11, 8) = 1408 blocks.
// ---------------------------------------------------------------------------
__global__ __launch_bounds__(256) void k3_out(const float* __restrict__ F,
                                              const float* __restrict__ M,
                                              float* __restrict__ outp) {
    __shared__ float Ft[32][68];   // [k][n]
    __shared__ float Ms[32][68];   // [k][i]
    const int t  = threadIdx.x;
    const int tx = t & 15;
    const int ty = t >> 4;
    const int n0 = blockIdx.x * 64;
    const int i0 = blockIdx.y * 64;
    const int ks = blockIdx.z;
    const int kbeg = ks * KLEN;
    const int kend = kbeg + KLEN;
    float acc[4][4] = {};

    for (int k0 = kbeg; k0 < kend; k0 += 32) {
        __syncthreads();
        {
            const int kk = t & 31;
            const int nb = t >> 5;
            const int k = k0 + kk;
#pragma unroll
            for (int rr = 0; rr < 8; ++rr) {
                const int n = nb * 8 + rr;
                Ft[kk][n] = (k < kend) ? F[(size_t)(n0 + n) * DIM + k] : 0.f;
            }
        }
        {
            const int i  = t & 63;
            const int kb = t >> 6;
#pragma unroll
            for (int rr = 0; rr < 8; ++rr) {
                const int kk = kb * 8 + rr;
                const int k = k0 + kk;
                Ms[kk][i] = (k < kend) ? M[(size_t)k * DPAD + i0 + i] : 0.f;
            }
        }
        __syncthreads();
#pragma unroll
        for (int kk = 0; kk < 32; ++kk) {
            const float4 a = *reinterpret_cast<const float4*>(&Ft[kk][ty * 4]);
            const float4 b = *reinterpret_cast<const float4*>(&Ms[kk][tx * 4]);
            acc[0][0] += a.x * b.x; acc[0][1] += a.x * b.y;
            acc[0][2] += a.x * b.z; acc[0][3] += a.x * b.w;
            acc[1][0] += a.y * b.x; acc[1][1] += a.y * b.y;
            acc[1][2] += a.y * b.z; acc[1][3] += a.y * b.w;
            acc[2][0] += a.z * b.x; acc[2][1] += a.z * b.y;
            acc[2][2] += a.z * b.z; acc[2][3] += a.z * b.w;
            acc[3][0] += a.w * b.x; acc[3][1] += a.w * b.y;
            acc[3][2] += a.w * b.z; acc[3][3] += a.w * b.w;
        }
    }

    float* op = outp + (size_t)ks * ((size_t)1024 * DIM);
#pragma unroll
    for (int r = 0; r < 4; ++r) {
        const int n = n0 + ty * 4 + r;
#pragma unroll
        for (int c = 0; c < 4; ++c) {
            const int i = i0 + tx * 4 + c;
            if (i < DIM) op[(size_t)n * DIM + i] = acc[r][c];
        }
    }
}

// ---------------------------------------------------------------------------
// k3r: out = sum of 8 K-slice partials. 680 blocks x 256 threads x float4.
// ---------------------------------------------------------------------------
__global__ __launch_bounds__(256) void k3_reduce(
        const float4* __restrict__ outp, float4* __restrict__ out) {
    const int idx = blockIdx.x * 256 + threadIdx.x;   // 174080 float4's
    const int N4 = 1024 * DIM / 4;
    float4 s = {0.f, 0.f, 0.f, 0.f};
#pragma unroll
    for (int p = 0; p < KSLICE; ++p) {
        const float4 a = outp[(size_t)p * N4 + idx];
        s.x += a.x; s.y += a.y; s.z += a.z; s.w += a.w;
    }
    out[idx] = s;
}

extern "C" void kernel_launch(void* const* d_in, const int* in_sizes, int n_in,
                              void* d_out, int out_size, void* d_ws, size_t ws_size,
                              hipStream_t stream) {
    const float* F  = (const float*)d_in[0];   // (1024, 680)
    const float* D  = (const float*)d_in[1];   // (48, 24, 48, 680)
    const float* qw = (const float*)d_in[2];   // (24,)
    float* out = (float*)d_out;
    char*  ws  = (char*)d_ws;

    uint4* awt = (uint4*)ws;                                    // 81.0 MiB bf16
    const size_t awt_bytes = (size_t)NCH * DPAD * 64 * 2;       // 84,934,656
    uint2* parts = (uint2*)(ws + awt_bytes);                    // 54.0 MiB bf16
    const size_t parts_bytes = (size_t)SPLITS * NTILE * 65536 * 2;  // 56,623,104
    float* M = (float*)(ws + awt_bytes + parts_bytes);          // 2.25 MiB fp32
    // k3 partials alias awt (dead after k2_gram; stream-ordered): 22.3 MiB
    float* outp = (float*)ws;

    k1_transpose<<<dim3(NCH / 4, DPAD / 64), 256, 0, stream>>>(D, qw, awt);
    k2_gram<<<dim3(SPLITS, NTILE), 512, 0, stream>>>(awt, parts);
    k2_reduce<<<dim3(32, NTILE), 256, 0, stream>>>(parts, M);
    k3_out<<<dim3(16, 11, KSLICE), 256, 0, stream>>>(F, M, outp);
    k3_reduce<<<dim3(1024 * DIM / 4 / 256), 256, 0, stream>>>(
        (const float4*)outp, (float4*)out);
}